// Round 1
// baseline (245.159 us; speedup 1.0000x reference)
//
#include <hip/hip_runtime.h>
#include <stdint.h>

#define TOKENS 8192
#define EDIM 512
#define HNUM 8
#define RNUM 16
#define DDIM 64
#define KDIM 512

typedef short v8s __attribute__((ext_vector_type(8)));
typedef float v4f __attribute__((ext_vector_type(4)));

__device__ inline float b2f(unsigned short u) {
    union { unsigned int i; float f; } c; c.i = ((unsigned int)u) << 16; return c.f;
}
__device__ inline unsigned short f2b(float f) {
    union { float f; unsigned int i; } c; c.f = f;
    unsigned int i = c.i + 0x7fffu + ((c.i >> 16) & 1u);
    return (unsigned short)(i >> 16);
}

// async global->LDS, 16B per lane; LDS dest = wave-uniform base + lane*16
#define GLD16(dst, src) \
    __builtin_amdgcn_global_load_lds((__attribute__((address_space(1))) void*)(src), \
                                     (__attribute__((address_space(3))) void*)(dst), 16, 0, 0)

// ---- fp32 -> bf16 convert, 5 segments in one launch (blockIdx.y picks) ----
__global__ __launch_bounds__(256)
void cvt5(const float* __restrict__ s0, const float* __restrict__ s1,
          const float* __restrict__ s2, const float* __restrict__ s3,
          const float* __restrict__ s4,
          unsigned short* __restrict__ d0, unsigned short* __restrict__ d1,
          unsigned short* __restrict__ d2, unsigned short* __restrict__ d3,
          unsigned short* __restrict__ d4,
          int n0, int n1, int n2, int n3, int n4)
{
    const float* s; unsigned short* d; int n;
    switch (blockIdx.y) {
        case 0: s = s0; d = d0; n = n0; break;
        case 1: s = s1; d = d1; n = n1; break;
        case 2: s = s2; d = d2; n = n2; break;
        case 3: s = s3; d = d3; n = n3; break;
        default: s = s4; d = d4; n = n4; break;
    }
    size_t base = (size_t)blockIdx.x * 2048 + (size_t)threadIdx.x * 8;
    if (base >= (size_t)n) return;
    const float4* sp = (const float4*)(s + base);
    float4 f0 = sp[0], f1 = sp[1];
    v8s o;
    o[0] = (short)f2b(f0.x); o[1] = (short)f2b(f0.y);
    o[2] = (short)f2b(f0.z); o[3] = (short)f2b(f0.w);
    o[4] = (short)f2b(f1.x); o[5] = (short)f2b(f1.y);
    o[6] = (short)f2b(f1.z); o[7] = (short)f2b(f1.w);
    *(v8s*)(d + base) = o;
}

// ---- small-GEMM path: 64x64 tiles, 1024 blocks -> 4 blocks/CU ----
// C[m,n] = sum_k A[m,k]*B[n,k]; K = 512.
// MODE 0: outH = bf16((C + bias[n]) * 0.125)   (Q projection)
// MODE 2: outF = C + bias[n]                   (O projection)
template <int MODE>
__global__ __launch_bounds__(256, 4)
void gemm64(const unsigned short* __restrict__ A,
            const unsigned short* __restrict__ B,
            const float* __restrict__ bias,
            float* __restrict__ outF,
            unsigned short* __restrict__ outH)
{
    __shared__ unsigned short As[64 * 32];
    __shared__ unsigned short Bs[64 * 32];

    const int tid  = threadIdx.x;
    const int w    = tid >> 6;
    const int lane = tid & 63;
    const int quad = lane >> 4;
    const int l16  = lane & 15;
    const int wm   = w >> 1, wn = w & 1;
    const int m0   = blockIdx.x * 64;
    const int n0   = blockIdx.y * 64;

    v4f acc[2][2];
#pragma unroll
    for (int i = 0; i < 2; ++i)
#pragma unroll
        for (int j = 0; j < 2; ++j)
            acc[i][j] = (v4f){0.f, 0.f, 0.f, 0.f};

    for (int kt = 0; kt < KDIM / 32; ++kt) {
        int c = w * 64 + lane;
        const unsigned short* sa = A + (size_t)(m0 + (c >> 2)) * KDIM + kt * 32 + (c & 3) * 8;
        GLD16(&As[w * 512], sa);
        const unsigned short* sb = B + (size_t)(n0 + (c >> 2)) * KDIM + kt * 32 + (c & 3) * 8;
        GLD16(&Bs[w * 512], sb);
        __syncthreads();

        v8s af[2], bf[2];
#pragma unroll
        for (int mt = 0; mt < 2; ++mt)
            af[mt] = *(const v8s*)&As[(wm * 32 + mt * 16 + l16) * 32 + quad * 8];
#pragma unroll
        for (int nt = 0; nt < 2; ++nt)
            bf[nt] = *(const v8s*)&Bs[(wn * 32 + nt * 16 + l16) * 32 + quad * 8];
#pragma unroll
        for (int mt = 0; mt < 2; ++mt)
#pragma unroll
            for (int nt = 0; nt < 2; ++nt)
                acc[mt][nt] = __builtin_amdgcn_mfma_f32_16x16x32_bf16(af[mt], bf[nt], acc[mt][nt], 0, 0, 0);
        __syncthreads();
    }

#pragma unroll
    for (int mt = 0; mt < 2; ++mt)
#pragma unroll
        for (int nt = 0; nt < 2; ++nt) {
            int col = n0 + wn * 32 + nt * 16 + l16;
            float bb = bias[col];
#pragma unroll
            for (int rg = 0; rg < 4; ++rg) {
                int row = m0 + wm * 32 + mt * 16 + quad * 4 + rg;
                float v = acc[mt][nt][rg] + bb;
                if (MODE == 0) outH[(size_t)row * EDIM + col] = f2b(v * 0.125f);
                else           outF[(size_t)row * EDIM + col] = v;
            }
        }
}

// ============================================================================
// V-GEMM, 8-phase pipelined (guide §5 m201-style template adapted).
//   C[m, token] = sum_k Wv[m,k] * value[token,k];  M = N = 8192, K = 512.
//   Tile 256x256, BK=64, 512 thr = 8 waves (wm 2 x wn 4); per-wave C = 128x64.
//   LDS: As[2][256*64] + Bs[2][256*64] bf16 = 128 KiB (double-buffered K-tiles).
//   Swizzle (T2): logical 16B k-granule g stored at physical g^(row&7); staging
//   pre-swizzles the GLOBAL source (gload_lds dest stays linear, rule #21);
//   ds_read applies the same XOR -> fragment reads ~2-way (free).
//   Schedule (T3/T4): per K-tile 4 phases, each = {ds_read frags | stage one
//   half-tile | barrier | lgkmcnt(0) | setprio(1) 16xMFMA setprio(0) | barrier}.
//   Issue plan (half-tiles; X.A0 = A rows 0-127 of tile X, etc.):
//     prologue: 0.A0 0.B1 0.A1 0.B0 1.A0 1.B1 ; vmcnt(4)
//     tile T:  P0(mq0,nq0) stages (T+1).A1   [slot dead since (T-1).P2]
//              P1(mq0,nq1) stages (T+1).B0   [dead since (T-1).P3]
//              P2(mq1,nq1) stages (T+2).A0   [this buf's A0 dead after P0]
//              P3(mq1,nq0) stages (T+2).B1   [this buf's B1 dead after P1]
//              end-P3: vmcnt(4) (=2 half-tiles in flight) -> tile T+1 landed.
//   Rule contraction epilogue unchanged from the 128² version (r = quad*4+reg,
//   shfl over quads, scrambled out1 layout = reference's reshape scramble).
// ============================================================================
__device__ __forceinline__ v8s ldfrag(const unsigned short* base, int r, int g) {
    return *(const v8s*)(base + (r << 6) + ((g ^ (r & 7)) << 3));
}

#define SCHED0 __builtin_amdgcn_sched_barrier(0)
#define BARX do { SCHED0; __builtin_amdgcn_s_barrier(); SCHED0; } while (0)
#define LGKM0 do { asm volatile("s_waitcnt lgkmcnt(0)" ::: "memory"); SCHED0; } while (0)
#define WAITV(n) do { asm volatile("s_waitcnt vmcnt(" #n ")" ::: "memory"); SCHED0; } while (0)

// stage one 128x64 half-tile: wave w does chunks 2w,2w+1 (rows 16w..16w+15)
#define STAGE_H(ldsArr, bufi, half_, gptr, rowbase, ktv) do { \
    const unsigned short* s_ = (gptr) + (size_t)((rowbase) + (half_) * 128 + (w << 4) + rsub) * KDIM \
                               + (ktv) * 64 + (gsw << 3); \
    GLD16(&ldsArr[bufi][(half_) * 8192 + (w << 10)], s_); \
    GLD16(&ldsArr[bufi][(half_) * 8192 + (w << 10) + 512], s_ + 8 * KDIM); \
} while (0)

#define LDA8(mq_) do { \
    _Pragma("unroll") \
    for (int mi = 0; mi < 4; ++mi) \
        _Pragma("unroll") \
        for (int ks = 0; ks < 2; ++ks) \
            af[mi * 2 + ks] = ldfrag(abase, wm * 64 + (mq_) * 128 + mi * 16 + l16, ks * 4 + quad); \
} while (0)

#define LDB4(nq_) do { \
    _Pragma("unroll") \
    for (int ni = 0; ni < 2; ++ni) \
        _Pragma("unroll") \
        for (int ks = 0; ks < 2; ++ks) \
            bf[ni * 2 + ks] = ldfrag(bbase, wn * 32 + (nq_) * 128 + ni * 16 + l16, ks * 4 + quad); \
} while (0)

#define MFMA16(mq_, nq_) do { \
    _Pragma("unroll") \
    for (int ks = 0; ks < 2; ++ks) \
        _Pragma("unroll") \
        for (int mi = 0; mi < 4; ++mi) \
            _Pragma("unroll") \
            for (int ni = 0; ni < 2; ++ni) \
                acc[(mq_) * 2 + (nq_)][mi][ni] = __builtin_amdgcn_mfma_f32_16x16x32_bf16( \
                    af[mi * 2 + ks], bf[ni * 2 + ks], acc[(mq_) * 2 + (nq_)][mi][ni], 0, 0, 0); \
} while (0)

__global__ __launch_bounds__(512, 2)
void gemm_v(const unsigned short* __restrict__ A,
            const unsigned short* __restrict__ B,
            const float* __restrict__ bias,
            unsigned short* __restrict__ outH,
            const float* __restrict__ attn)
{
    __shared__ unsigned short As[2][16384];
    __shared__ unsigned short Bs[2][16384];

    const int tid  = threadIdx.x;
    const int w    = tid >> 6;          // wave 0..7
    const int lane = tid & 63;
    const int quad = lane >> 4;
    const int l16  = lane & 15;
    const int wm   = w >> 2;            // 0..1
    const int wn   = w & 3;             // 0..3
    const int rsub = lane >> 3;         // 0..7 (staging row-in-chunk)
    const int gsw  = (lane & 7) ^ rsub; // pre-swizzled source k-granule

    // T1: XCD-contiguous bijective swizzle (1024 blocks, 8 XCDs)
    const int id = ((blockIdx.x & 7) << 7) | (blockIdx.x >> 3);
    const int m0 = (id & 31) << 8;      // Wv-row tile
    const int n0 = (id >> 5) << 8;      // token tile

    v4f acc[4][4][2];
#pragma unroll
    for (int q = 0; q < 4; ++q)
#pragma unroll
        for (int mi = 0; mi < 4; ++mi)
#pragma unroll
            for (int ni = 0; ni < 2; ++ni)
                acc[q][mi][ni] = (v4f){0.f, 0.f, 0.f, 0.f};

    v8s af[8], bf[4];

    // ---- prologue ----
    STAGE_H(As, 0, 0, A, m0, 0);   // 0.A0
    STAGE_H(Bs, 0, 1, B, n0, 0);   // 0.B1
    STAGE_H(As, 0, 1, A, m0, 0);   // 0.A1
    STAGE_H(Bs, 0, 0, B, n0, 0);   // 0.B0
    STAGE_H(As, 1, 0, A, m0, 1);   // 1.A0
    STAGE_H(Bs, 1, 1, B, n0, 1);   // 1.B1
    WAITV(4);                      // tile 0 fully landed; 2 half-tiles in flight
    BARX;

    for (int T = 0; T < KDIM / 64; ++T) {
        const unsigned short* abase = &As[T & 1][0];
        const unsigned short* bbase = &Bs[T & 1][0];
        const int bn_ = (T & 1) ^ 1;

        // P0 (mq0,nq0)
        LDA8(0); LDB4(0);
        if (T + 1 < 8) STAGE_H(As, bn_, 1, A, m0, T + 1);      // (T+1).A1
        BARX; LGKM0;
        __builtin_amdgcn_s_setprio(1); MFMA16(0, 0); __builtin_amdgcn_s_setprio(0);
        BARX;

        // P1 (mq0,nq1): A frags reused from regs
        LDB4(1);
        if (T + 1 < 8) STAGE_H(Bs, bn_, 0, B, n0, T + 1);      // (T+1).B0
        BARX; LGKM0;
        __builtin_amdgcn_s_setprio(1); MFMA16(0, 1); __builtin_amdgcn_s_setprio(0);
        BARX;

        // P2 (mq1,nq1): B frags reused
        LDA8(1);
        if (T + 2 < 8) STAGE_H(As, T & 1, 0, A, m0, T + 2);    // (T+2).A0 (dead slot)
        BARX; LGKM0;
        __builtin_amdgcn_s_setprio(1); MFMA16(1, 1); __builtin_amdgcn_s_setprio(0);
        BARX;

        // P3 (mq1,nq0)
        LDB4(0);
        if (T + 2 < 8) STAGE_H(Bs, T & 1, 1, B, n0, T + 2);    // (T+2).B1 (dead slot)
        BARX; LGKM0;
        __builtin_amdgcn_s_setprio(1); MFMA16(1, 0); __builtin_amdgcn_s_setprio(0);
        if (T < 6) { WAITV(4); } else { WAITV(0); }            // next tile landed
        BARX;
    }

    // ---- epilogue: rule contraction + scrambled out1 store ----
    unsigned short* Osp = &As[0][0];    // 8 KiB, overlays dead As[0]
    const int h  = m0 >> 10;
    const int d0 = (m0 >> 4) & 63;
#pragma unroll
    for (int mq = 0; mq < 2; ++mq)
#pragma unroll
        for (int nq = 0; nq < 2; ++nq)
#pragma unroll
            for (int mi = 0; mi < 4; ++mi) {
                float4 bias4 = *(const float4*)&bias[m0 + mq * 128 + wm * 64 + mi * 16 + quad * 4];
#pragma unroll
                for (int ni = 0; ni < 2; ++ni) {
                    int tloc  = nq * 128 + wn * 32 + ni * 16 + l16;
                    float4 av = *(const float4*)&attn[(size_t)(n0 + tloc) * (HNUM * RNUM) + h * RNUM + quad * 4];
                    v4f a = acc[mq * 2 + nq][mi][ni];
                    float val = (a[0] + bias4.x) * av.x + (a[1] + bias4.y) * av.y
                              + (a[2] + bias4.z) * av.z + (a[3] + bias4.w) * av.w;
                    val += __shfl_xor(val, 16);
                    val += __shfl_xor(val, 32);
                    if (quad == 0)
                        Osp[tloc * 16 + (mq * 8 + wm * 4 + mi)] = f2b(val * 0.125f);
                }
            }
    __syncthreads();
    {
        int tl = tid >> 1, hf = tid & 1;
        int sg = n0 + tl;               // global token
        int g  = (sg >> 11) * 2048 + h * 256 + ((sg & 2047) >> 3);
        int j  = (sg & 7) * 64 + d0 + hf * 8;
        *(v8s*)&outH[(size_t)g * EDIM + j] = *(const v8s*)&Osp[tl * 16 + hf * 8];
    }
}

// per (token, head): z_r = -0.5*mean_d(((q-k)/w)^2), softmax over 16 rules.
// grid (TOKENS/16, HNUM), block 256 = 16 tokens x 16 rules.
#define RST 72   // padded LDS row stride (floats)
__global__ __launch_bounds__(256)
void rules_softmax(const unsigned short* __restrict__ q,  // bf16 (8192 x 512)
                   const float* __restrict__ rk,
                   const float* __restrict__ rw,
                   float* __restrict__ attn)
{
    __shared__ float ql[16 * RST];
    __shared__ float rkl[16 * RST];
    __shared__ float iwl[16 * RST];
    const int h   = blockIdx.y;
    const int t0  = blockIdx.x * 16;
    const int tid = threadIdx.x;

#pragma unroll
    for (int i = 0; i < 4; ++i) {
        int jj = tid + i * 256;
        int r = jj >> 6, d = jj & 63;
        rkl[r * RST + d] = rk[h * (RNUM * DDIM) + jj];
        float wv = rw[h * (RNUM * DDIM) + jj];
        iwl[r * RST + d] = 1.0f / (wv * wv);
    }
    {
        int jj = tid * 4;
        int row = jj >> 6, d = jj & 63;
        const unsigned short* src = q + (size_t)(t0 + row) * EDIM + h * DDIM + d;
        unsigned short u0 = src[0], u1 = src[1], u2 = src[2], u3 = src[3];
        ql[row * RST + d + 0] = b2f(u0);
        ql[row * RST + d + 1] = b2f(u1);
        ql[row * RST + d + 2] = b2f(u2);
        ql[row * RST + d + 3] = b2f(u3);
    }
    __syncthreads();

    const int tl = tid >> 4;
    const int r  = tid & 15;
    const float* qrow = &ql[tl * RST];
    const float* krow = &rkl[r * RST];
    const float* wrow = &iwl[r * RST];
    float z = 0.f;
#pragma unroll
    for (int d4 = 0; d4 < 16; ++d4) {
        float4 qv = *(const float4*)&qrow[d4 * 4];
        float4 kv = *(const float4*)&krow[d4 * 4];
        float4 wv = *(const float4*)&wrow[d4 * 4];
        float a0 = qv.x - kv.x; z += a0 * a0 * wv.x;
        float a1 = qv.y - kv.y; z += a1 * a1 * wv.y;
        float a2 = qv.z - kv.z; z += a2 * a2 * wv.z;
        float a3 = qv.w - kv.w; z += a3 * a3 * wv.w;
    }
    z *= (-0.5f / 64.f);
    float mx = z;
#pragma unroll
    for (int s = 1; s < 16; s <<= 1) mx = fmaxf(mx, __shfl_xor(mx, s));
    float e = __expf(z - mx);
    float sum = e;
#pragma unroll
    for (int s = 1; s < 16; s <<= 1) sum += __shfl_xor(sum, s);
    attn[(size_t)(t0 + tl) * (HNUM * RNUM) + h * RNUM + r] = e / sum;
}

extern "C" void kernel_launch(void* const* d_in, const int* in_sizes, int n_in,
                              void* d_out, int out_size, void* d_ws, size_t ws_size,
                              hipStream_t stream) {
    const float* query = (const float*)d_in[0];
    // d_in[1] = key (unused by the reference)
    const float* value = (const float*)d_in[2];
    const float* Wq = (const float*)d_in[3];
    const float* bq = (const float*)d_in[4];
    const float* Wv = (const float*)d_in[5];
    const float* bv = (const float*)d_in[6];
    const float* Wo = (const float*)d_in[7];
    const float* bo = (const float*)d_in[8];
    const float* rk = (const float*)d_in[9];
    const float* rw = (const float*)d_in[10];

    char* ws = (char*)d_ws;
    unsigned short* qbf  = (unsigned short*)(ws);                       //  8 MiB: query bf16
    unsigned short* vbf  = (unsigned short*)(ws + (size_t)( 8 << 20));  //  8 MiB: value bf16
    unsigned short* Wqb  = (unsigned short*)(ws + (size_t)(16 << 20));  // 0.5 MiB
    unsigned short* Wvb  = (unsigned short*)(ws + (size_t)(17 << 20));  //  8 MiB
    unsigned short* Wob  = (unsigned short*)(ws + (size_t)(25 << 20));  // 0.5 MiB
    unsigned short* out1 = (unsigned short*)(ws + (size_t)(26 << 20));  //  8 MiB: scrambled bf16
    unsigned short* qf   = (unsigned short*)(ws + (size_t)(34 << 20));  //  8 MiB: q bf16
    float* attn          = (float*)(ws + (size_t)(42 << 20));           //  4 MiB: attn fp32

    dim3 blk(256);
    // 0) fp32 -> bf16 conversions
    cvt5<<<dim3(2048, 5), blk, 0, stream>>>(query, value, Wv, Wq, Wo,
                                            qbf, vbf, Wvb, Wqb, Wob,
                                            TOKENS * EDIM, TOKENS * EDIM, EDIM * RNUM * EDIM,
                                            EDIM * EDIM, EDIM * EDIM);
    // 1) q = bf16((query @ Wq^T + bq) * D^-0.5)   [64x64 tiles, 1024 blocks]
    gemm64<0><<<dim3(TOKENS / 64, EDIM / 64), blk, 0, stream>>>(qbf, Wqb, bq, nullptr, qf);
    // 2) fuzzy rule attention weights
    rules_softmax<<<dim3(TOKENS / 16, HNUM), blk, 0, stream>>>(qf, rk, rw, attn);
    // 3) transposed V-GEMM + rule contraction -> scrambled out1  [256² 8-phase]
    gemm_v<<<dim3(1024), dim3(512), 0, stream>>>(Wvb, vbf, bv, out1, attn);
    // 4) final projection -> d_out (fp32)  [64x64 tiles, 1024 blocks]
    gemm64<2><<<dim3(TOKENS / 64, EDIM / 64), blk, 0, stream>>>(out1, Wob, bo, (float*)d_out, nullptr);
}

// Round 2
// 230.024 us; speedup vs baseline: 1.0658x; 1.0658x over previous
//
#include <hip/hip_runtime.h>
#include <stdint.h>

#define TOKENS 8192
#define EDIM 512
#define HNUM 8
#define RNUM 16
#define DDIM 64
#define KDIM 512

typedef short v8s __attribute__((ext_vector_type(8)));
typedef float v4f __attribute__((ext_vector_type(4)));

__device__ inline float b2f(unsigned short u) {
    union { unsigned int i; float f; } c; c.i = ((unsigned int)u) << 16; return c.f;
}
__device__ inline unsigned short f2b(float f) {
    union { float f; unsigned int i; } c; c.f = f;
    unsigned int i = c.i + 0x7fffu + ((c.i >> 16) & 1u);
    return (unsigned short)(i >> 16);
}

// async global->LDS, 16B per lane; LDS dest = wave-uniform base + lane*16
#define GLD16(dst, src) \
    __builtin_amdgcn_global_load_lds((__attribute__((address_space(1))) void*)(src), \
                                     (__attribute__((address_space(3))) void*)(dst), 16, 0, 0)

// ---- fp32 -> bf16 convert, 5 segments in one launch (blockIdx.y picks) ----
__global__ __launch_bounds__(256)
void cvt5(const float* __restrict__ s0, const float* __restrict__ s1,
          const float* __restrict__ s2, const float* __restrict__ s3,
          const float* __restrict__ s4,
          unsigned short* __restrict__ d0, unsigned short* __restrict__ d1,
          unsigned short* __restrict__ d2, unsigned short* __restrict__ d3,
          unsigned short* __restrict__ d4,
          int n0, int n1, int n2, int n3, int n4)
{
    const float* s; unsigned short* d; int n;
    switch (blockIdx.y) {
        case 0: s = s0; d = d0; n = n0; break;
        case 1: s = s1; d = d1; n = n1; break;
        case 2: s = s2; d = d2; n = n2; break;
        case 3: s = s3; d = d3; n = n3; break;
        default: s = s4; d = d4; n = n4; break;
    }
    size_t base = (size_t)blockIdx.x * 2048 + (size_t)threadIdx.x * 8;
    if (base >= (size_t)n) return;
    const float4* sp = (const float4*)(s + base);
    float4 f0 = sp[0], f1 = sp[1];
    v8s o;
    o[0] = (short)f2b(f0.x); o[1] = (short)f2b(f0.y);
    o[2] = (short)f2b(f0.z); o[3] = (short)f2b(f0.w);
    o[4] = (short)f2b(f1.x); o[5] = (short)f2b(f1.y);
    o[6] = (short)f2b(f1.z); o[7] = (short)f2b(f1.w);
    *(v8s*)(d + base) = o;
}

// ---- small-GEMM path: 64x64 tiles, 1024 blocks -> 4 blocks/CU ----
// C[m,n] = sum_k A[m,k]*B[n,k]; K = 512.
// MODE 0: outH = bf16((C + bias[n]) * 0.125)   (Q projection)
// MODE 2: outF = C + bias[n]                   (O projection)
template <int MODE>
__global__ __launch_bounds__(256, 4)
void gemm64(const unsigned short* __restrict__ A,
            const unsigned short* __restrict__ B,
            const float* __restrict__ bias,
            float* __restrict__ outF,
            unsigned short* __restrict__ outH)
{
    __shared__ unsigned short As[64 * 32];
    __shared__ unsigned short Bs[64 * 32];

    const int tid  = threadIdx.x;
    const int w    = tid >> 6;
    const int lane = tid & 63;
    const int quad = lane >> 4;
    const int l16  = lane & 15;
    const int wm   = w >> 1, wn = w & 1;
    const int m0   = blockIdx.x * 64;
    const int n0   = blockIdx.y * 64;

    v4f acc[2][2];
#pragma unroll
    for (int i = 0; i < 2; ++i)
#pragma unroll
        for (int j = 0; j < 2; ++j)
            acc[i][j] = (v4f){0.f, 0.f, 0.f, 0.f};

    for (int kt = 0; kt < KDIM / 32; ++kt) {
        int c = w * 64 + lane;
        const unsigned short* sa = A + (size_t)(m0 + (c >> 2)) * KDIM + kt * 32 + (c & 3) * 8;
        GLD16(&As[w * 512], sa);
        const unsigned short* sb = B + (size_t)(n0 + (c >> 2)) * KDIM + kt * 32 + (c & 3) * 8;
        GLD16(&Bs[w * 512], sb);
        __syncthreads();

        v8s af[2], bf[2];
#pragma unroll
        for (int mt = 0; mt < 2; ++mt)
            af[mt] = *(const v8s*)&As[(wm * 32 + mt * 16 + l16) * 32 + quad * 8];
#pragma unroll
        for (int nt = 0; nt < 2; ++nt)
            bf[nt] = *(const v8s*)&Bs[(wn * 32 + nt * 16 + l16) * 32 + quad * 8];
#pragma unroll
        for (int mt = 0; mt < 2; ++mt)
#pragma unroll
            for (int nt = 0; nt < 2; ++nt)
                acc[mt][nt] = __builtin_amdgcn_mfma_f32_16x16x32_bf16(af[mt], bf[nt], acc[mt][nt], 0, 0, 0);
        __syncthreads();
    }

#pragma unroll
    for (int mt = 0; mt < 2; ++mt)
#pragma unroll
        for (int nt = 0; nt < 2; ++nt) {
            int col = n0 + wn * 32 + nt * 16 + l16;
            float bb = bias[col];
#pragma unroll
            for (int rg = 0; rg < 4; ++rg) {
                int row = m0 + wm * 32 + mt * 16 + quad * 4 + rg;
                float v = acc[mt][nt][rg] + bb;
                if (MODE == 0) outH[(size_t)row * EDIM + col] = f2b(v * 0.125f);
                else           outF[(size_t)row * EDIM + col] = v;
            }
        }
}

// ============================================================================
// V-GEMM, 256x256x(BK=64) 8-wave 4-phase pipeline (m201 template, de-pinned).
//   C[m, token] = sum_k Wv[m,k] * value[token,k];  M = N = 8192, K = 512.
//   NO sched_barrier(0) anywhere (m141: order-pinning = 40% regression).
//   Plain s_barrier; ordering safety comes from the asm waitcnts' "memory"
//   clobbers adjacent to each barrier (ds_reads/GLD16 can't cross a phase
//   boundary hazardously; reg-only MFMA hoisting is harmless).
//   Phases per K-tile T (buf = T&1, obuf = buf^1):
//     P0: LDA8(0)->af, LDB4(0)->bf0 | stage (T+1).A1->obuf | bar lgkm0 MFMA(0,0) bar
//     P1: LDB4(1)->bf1              | stage (T+1).B0->obuf | bar lgkm0 MFMA(0,1) bar
//     P2: LDA8(1)->af               | stage (T+2).A0->buf  | bar lgkm0 MFMA(1,1) bar
//     P3: (no LDS reads, reuse bf0) | stage (T+2).B1->buf  | bar lgkm0 MFMA(1,0)
//         vmcnt(4) [tile T+1 landed; 2 half-tiles in flight] bar
//   Swizzle (T2): logical 16B k-granule g stored at phys g^(row&7); staging
//   pre-swizzles the GLOBAL source (linear gload_lds dest, rule #21).
//   XCD map (T1): per-XCD concurrent window = 8m x 4n tiles (3 MB, L2-fits).
// ============================================================================
__device__ __forceinline__ v8s ldfrag(const unsigned short* base, int r, int g) {
    return *(const v8s*)(base + (r << 6) + ((g ^ (r & 7)) << 3));
}

#define BAR   __builtin_amdgcn_s_barrier()
#define LGKM0 asm volatile("s_waitcnt lgkmcnt(0)" ::: "memory")
#define WAITV(n) asm volatile("s_waitcnt vmcnt(" #n ")" ::: "memory")

// stage one 128x64 half-tile: wave w does rows (half*128 + w*16 .. +15)
#define STAGE_H(ldsArr, bufi, half_, gptr, rowbase, ktv) do { \
    const unsigned short* s_ = (gptr) + (size_t)((rowbase) + (half_) * 128 + (w << 4) + rsub) * KDIM \
                               + (ktv) * 64 + (gsw << 3); \
    GLD16(&ldsArr[bufi][(half_) * 8192 + (w << 10)], s_); \
    GLD16(&ldsArr[bufi][(half_) * 8192 + (w << 10) + 512], s_ + 8 * KDIM); \
} while (0)

#define LDA8(mq_) do { \
    _Pragma("unroll") \
    for (int mi = 0; mi < 4; ++mi) \
        _Pragma("unroll") \
        for (int ks = 0; ks < 2; ++ks) \
            af[mi * 2 + ks] = ldfrag(abase, wm * 64 + (mq_) * 128 + mi * 16 + l16, ks * 4 + quad); \
} while (0)

#define LDB4(nq_, dst) do { \
    _Pragma("unroll") \
    for (int ni = 0; ni < 2; ++ni) \
        _Pragma("unroll") \
        for (int ks = 0; ks < 2; ++ks) \
            dst[ni * 2 + ks] = ldfrag(bbase, wn * 32 + (nq_) * 128 + ni * 16 + l16, ks * 4 + quad); \
} while (0)

#define MFMA16(ai_, bfr) do { \
    _Pragma("unroll") \
    for (int ks = 0; ks < 2; ++ks) \
        _Pragma("unroll") \
        for (int mi = 0; mi < 4; ++mi) \
            _Pragma("unroll") \
            for (int ni = 0; ni < 2; ++ni) \
                acc[ai_][mi][ni] = __builtin_amdgcn_mfma_f32_16x16x32_bf16( \
                    af[mi * 2 + ks], bfr[ni * 2 + ks], acc[ai_][mi][ni], 0, 0, 0); \
} while (0)

__global__ __launch_bounds__(512, 2)
void gemm_v(const unsigned short* __restrict__ A,
            const unsigned short* __restrict__ B,
            const float* __restrict__ bias,
            unsigned short* __restrict__ outH,
            const float* __restrict__ attn)
{
    __shared__ unsigned short As[2][16384];
    __shared__ unsigned short Bs[2][16384];

    const int tid  = threadIdx.x;
    const int w    = tid >> 6;          // wave 0..7
    const int lane = tid & 63;
    const int quad = lane >> 4;
    const int l16  = lane & 15;
    const int wm   = w >> 2;            // 0..1
    const int wn   = w & 3;             // 0..3
    const int rsub = lane >> 3;         // 0..7 (staging row-in-chunk)
    const int gsw  = (lane & 7) ^ rsub; // pre-swizzled source k-granule

    // T1: XCD c = bx&7 owns n-tiles 4c..4c+3; within XCD, concurrent window
    // of ~32 blocks = 8 m-tiles x 4 n-tiles (2 MB A + 1 MB B, L2-resident).
    const int c  = blockIdx.x & 7;
    const int j  = blockIdx.x >> 3;           // 0..127
    const int mb = (j & 7) | ((j >> 5) << 3); // 0..31
    const int nb = (j >> 3) & 3;              // 0..3
    const int m0 = mb << 8;
    const int n0 = (c * 4 + nb) << 8;

    v4f acc[4][4][2];
#pragma unroll
    for (int q = 0; q < 4; ++q)
#pragma unroll
        for (int mi = 0; mi < 4; ++mi)
#pragma unroll
            for (int ni = 0; ni < 2; ++ni)
                acc[q][mi][ni] = (v4f){0.f, 0.f, 0.f, 0.f};

    v8s af[8], bf0[4], bf1[4];

    // ---- prologue: tile 0 fully, then 1.A0, 1.B1 ----
    STAGE_H(As, 0, 0, A, m0, 0);   // 0.A0
    STAGE_H(Bs, 0, 0, B, n0, 0);   // 0.B0
    STAGE_H(As, 0, 1, A, m0, 0);   // 0.A1
    STAGE_H(Bs, 0, 1, B, n0, 0);   // 0.B1
    STAGE_H(As, 1, 0, A, m0, 1);   // 1.A0
    STAGE_H(Bs, 1, 1, B, n0, 1);   // 1.B1
    WAITV(4);                      // tile 0 landed; 2 half-tiles in flight
    BAR;

#pragma unroll
    for (int T = 0; T < KDIM / 64; ++T) {
        const unsigned short* abase = &As[T & 1][0];
        const unsigned short* bbase = &Bs[T & 1][0];
        const int bn_ = (T & 1) ^ 1;

        // P0 (mq0,nq0)
        LDA8(0); LDB4(0, bf0);
        if (T + 1 < 8) STAGE_H(As, bn_, 1, A, m0, T + 1);      // (T+1).A1
        BAR; LGKM0;
        __builtin_amdgcn_s_setprio(1); MFMA16(0, bf0); __builtin_amdgcn_s_setprio(0);
        BAR;

        // P1 (mq0,nq1): A frags reused from regs
        LDB4(1, bf1);
        if (T + 1 < 8) STAGE_H(Bs, bn_, 0, B, n0, T + 1);      // (T+1).B0
        BAR; LGKM0;
        __builtin_amdgcn_s_setprio(1); MFMA16(1, bf1); __builtin_amdgcn_s_setprio(0);
        BAR;

        // P2 (mq1,nq1): B frags reused from bf1
        LDA8(1);
        if (T + 2 < 8) STAGE_H(As, T & 1, 0, A, m0, T + 2);    // (T+2).A0 (dead slot)
        BAR; LGKM0;
        __builtin_amdgcn_s_setprio(1); MFMA16(3, bf1); __builtin_amdgcn_s_setprio(0);
        BAR;

        // P3 (mq1,nq0): no LDS reads — B0 frags still live in bf0
        if (T + 2 < 8) STAGE_H(Bs, T & 1, 1, B, n0, T + 2);    // (T+2).B1 (dead slot)
        BAR; LGKM0;
        __builtin_amdgcn_s_setprio(1); MFMA16(2, bf0); __builtin_amdgcn_s_setprio(0);
        if (T < 6) { WAITV(4); } else { WAITV(0); }            // next tile landed
        BAR;
    }

    // ---- epilogue: rule contraction + scrambled out1 store ----
    unsigned short* Osp = &As[0][0];    // 8 KiB, overlays dead As[0]
    const int h  = m0 >> 10;
    const int d0 = (m0 >> 4) & 63;
#pragma unroll
    for (int mq = 0; mq < 2; ++mq)
#pragma unroll
        for (int nq = 0; nq < 2; ++nq)
#pragma unroll
            for (int mi = 0; mi < 4; ++mi) {
                float4 bias4 = *(const float4*)&bias[m0 + mq * 128 + wm * 64 + mi * 16 + quad * 4];
#pragma unroll
                for (int ni = 0; ni < 2; ++ni) {
                    int tloc  = nq * 128 + wn * 32 + ni * 16 + l16;
                    float4 av = *(const float4*)&attn[(size_t)(n0 + tloc) * (HNUM * RNUM) + h * RNUM + quad * 4];
                    v4f a = acc[mq * 2 + nq][mi][ni];
                    float val = (a[0] + bias4.x) * av.x + (a[1] + bias4.y) * av.y
                              + (a[2] + bias4.z) * av.z + (a[3] + bias4.w) * av.w;
                    val += __shfl_xor(val, 16);
                    val += __shfl_xor(val, 32);
                    if (quad == 0)
                        Osp[tloc * 16 + (mq * 8 + wm * 4 + mi)] = f2b(val * 0.125f);
                }
            }
    __syncthreads();
    {
        int tl = tid >> 1, hf = tid & 1;
        int sg = n0 + tl;               // global token
        int g  = (sg >> 11) * 2048 + h * 256 + ((sg & 2047) >> 3);
        int jx = (sg & 7) * 64 + d0 + hf * 8;
        *(v8s*)&outH[(size_t)g * EDIM + jx] = *(const v8s*)&Osp[tl * 16 + hf * 8];
    }
}

// per (token, head): z_r = -0.5*mean_d(((q-k)/w)^2), softmax over 16 rules.
// grid (TOKENS/16, HNUM), block 256 = 16 tokens x 16 rules.
#define RST 72   // padded LDS row stride (floats)
__global__ __launch_bounds__(256)
void rules_softmax(const unsigned short* __restrict__ q,  // bf16 (8192 x 512)
                   const float* __restrict__ rk,
                   const float* __restrict__ rw,
                   float* __restrict__ attn)
{
    __shared__ float ql[16 * RST];
    __shared__ float rkl[16 * RST];
    __shared__ float iwl[16 * RST];
    const int h   = blockIdx.y;
    const int t0  = blockIdx.x * 16;
    const int tid = threadIdx.x;

#pragma unroll
    for (int i = 0; i < 4; ++i) {
        int jj = tid + i * 256;
        int r = jj >> 6, d = jj & 63;
        rkl[r * RST + d] = rk[h * (RNUM * DDIM) + jj];
        float wv = rw[h * (RNUM * DDIM) + jj];
        iwl[r * RST + d] = 1.0f / (wv * wv);
    }
    {
        int jj = tid * 4;
        int row = jj >> 6, d = jj & 63;
        const unsigned short* src = q + (size_t)(t0 + row) * EDIM + h * DDIM + d;
        unsigned short u0 = src[0], u1 = src[1], u2 = src[2], u3 = src[3];
        ql[row * RST + d + 0] = b2f(u0);
        ql[row * RST + d + 1] = b2f(u1);
        ql[row * RST + d + 2] = b2f(u2);
        ql[row * RST + d + 3] = b2f(u3);
    }
    __syncthreads();

    const int tl = tid >> 4;
    const int r  = tid & 15;
    const float* qrow = &ql[tl * RST];
    const float* krow = &rkl[r * RST];
    const float* wrow = &iwl[r * RST];
    float z = 0.f;
#pragma unroll
    for (int d4 = 0; d4 < 16; ++d4) {
        float4 qv = *(const float4*)&qrow[d4 * 4];
        float4 kv = *(const float4*)&krow[d4 * 4];
        float4 wv = *(const float4*)&wrow[d4 * 4];
        float a0 = qv.x - kv.x; z += a0 * a0 * wv.x;
        float a1 = qv.y - kv.y; z += a1 * a1 * wv.y;
        float a2 = qv.z - kv.z; z += a2 * a2 * wv.z;
        float a3 = qv.w - kv.w; z += a3 * a3 * wv.w;
    }
    z *= (-0.5f / 64.f);
    float mx = z;
#pragma unroll
    for (int s = 1; s < 16; s <<= 1) mx = fmaxf(mx, __shfl_xor(mx, s));
    float e = __expf(z - mx);
    float sum = e;
#pragma unroll
    for (int s = 1; s < 16; s <<= 1) sum += __shfl_xor(sum, s);
    attn[(size_t)(t0 + tl) * (HNUM * RNUM) + h * RNUM + r] = e / sum;
}

extern "C" void kernel_launch(void* const* d_in, const int* in_sizes, int n_in,
                              void* d_out, int out_size, void* d_ws, size_t ws_size,
                              hipStream_t stream) {
    const float* query = (const float*)d_in[0];
    // d_in[1] = key (unused by the reference)
    const float* value = (const float*)d_in[2];
    const float* Wq = (const float*)d_in[3];
    const float* bq = (const float*)d_in[4];
    const float* Wv = (const float*)d_in[5];
    const float* bv = (const float*)d_in[6];
    const float* Wo = (const float*)d_in[7];
    const float* bo = (const float*)d_in[8];
    const float* rk = (const float*)d_in[9];
    const float* rw = (const float*)d_in[10];

    char* ws = (char*)d_ws;
    unsigned short* qbf  = (unsigned short*)(ws);                       //  8 MiB: query bf16
    unsigned short* vbf  = (unsigned short*)(ws + (size_t)( 8 << 20));  //  8 MiB: value bf16
    unsigned short* Wqb  = (unsigned short*)(ws + (size_t)(16 << 20));  // 0.5 MiB
    unsigned short* Wvb  = (unsigned short*)(ws + (size_t)(17 << 20));  //  8 MiB
    unsigned short* Wob  = (unsigned short*)(ws + (size_t)(25 << 20));  // 0.5 MiB
    unsigned short* out1 = (unsigned short*)(ws + (size_t)(26 << 20));  //  8 MiB: scrambled bf16
    unsigned short* qf   = (unsigned short*)(ws + (size_t)(34 << 20));  //  8 MiB: q bf16
    float* attn          = (float*)(ws + (size_t)(42 << 20));           //  4 MiB: attn fp32

    dim3 blk(256);
    // 0) fp32 -> bf16 conversions
    cvt5<<<dim3(2048, 5), blk, 0, stream>>>(query, value, Wv, Wq, Wo,
                                            qbf, vbf, Wvb, Wqb, Wob,
                                            TOKENS * EDIM, TOKENS * EDIM, EDIM * RNUM * EDIM,
                                            EDIM * EDIM, EDIM * EDIM);
    // 1) q = bf16((query @ Wq^T + bq) * D^-0.5)   [64x64 tiles, 1024 blocks]
    gemm64<0><<<dim3(TOKENS / 64, EDIM / 64), blk, 0, stream>>>(qbf, Wqb, bq, nullptr, qf);
    // 2) fuzzy rule attention weights
    rules_softmax<<<dim3(TOKENS / 16, HNUM), blk, 0, stream>>>(qf, rk, rw, attn);
    // 3) transposed V-GEMM + rule contraction -> scrambled out1  [256² 4-phase]
    gemm_v<<<dim3(1024), dim3(512), 0, stream>>>(Wvb, vbf, bv, out1, attn);
    // 4) final projection -> d_out (fp32)  [64x64 tiles, 1024 blocks]
    gemm64<2><<<dim3(TOKENS / 64, EDIM / 64), blk, 0, stream>>>(out1, Wob, bo, (float*)d_out, nullptr);
}

// Round 3
// 227.326 us; speedup vs baseline: 1.0784x; 1.0119x over previous
//
#include <hip/hip_runtime.h>
#include <stdint.h>

#define TOKENS 8192
#define EDIM 512
#define HNUM 8
#define RNUM 16
#define DDIM 64
#define KDIM 512

typedef short v8s __attribute__((ext_vector_type(8)));
typedef float v4f __attribute__((ext_vector_type(4)));

__device__ inline float b2f(unsigned short u) {
    union { unsigned int i; float f; } c; c.i = ((unsigned int)u) << 16; return c.f;
}
__device__ inline unsigned short f2b(float f) {
    union { float f; unsigned int i; } c; c.f = f;
    unsigned int i = c.i + 0x7fffu + ((c.i >> 16) & 1u);
    return (unsigned short)(i >> 16);
}

// async global->LDS, 16B per lane; LDS dest = wave-uniform base + lane*16
#define GLD16(dst, src) \
    __builtin_amdgcn_global_load_lds((__attribute__((address_space(1))) void*)(src), \
                                     (__attribute__((address_space(3))) void*)(dst), 16, 0, 0)

// ---- fp32 -> bf16 convert, 5 segments in one launch (blockIdx.y picks) ----
__global__ __launch_bounds__(256)
void cvt5(const float* __restrict__ s0, const float* __restrict__ s1,
          const float* __restrict__ s2, const float* __restrict__ s3,
          const float* __restrict__ s4,
          unsigned short* __restrict__ d0, unsigned short* __restrict__ d1,
          unsigned short* __restrict__ d2, unsigned short* __restrict__ d3,
          unsigned short* __restrict__ d4,
          int n0, int n1, int n2, int n3, int n4)
{
    const float* s; unsigned short* d; int n;
    switch (blockIdx.y) {
        case 0: s = s0; d = d0; n = n0; break;
        case 1: s = s1; d = d1; n = n1; break;
        case 2: s = s2; d = d2; n = n2; break;
        case 3: s = s3; d = d3; n = n3; break;
        default: s = s4; d = d4; n = n4; break;
    }
    size_t base = (size_t)blockIdx.x * 2048 + (size_t)threadIdx.x * 8;
    if (base >= (size_t)n) return;
    const float4* sp = (const float4*)(s + base);
    float4 f0 = sp[0], f1 = sp[1];
    v8s o;
    o[0] = (short)f2b(f0.x); o[1] = (short)f2b(f0.y);
    o[2] = (short)f2b(f0.z); o[3] = (short)f2b(f0.w);
    o[4] = (short)f2b(f1.x); o[5] = (short)f2b(f1.y);
    o[6] = (short)f2b(f1.z); o[7] = (short)f2b(f1.w);
    *(v8s*)(d + base) = o;
}

// ---- small-GEMM path: 64x64 tiles, 1024 blocks -> 4 blocks/CU ----
// C[m,n] = sum_k A[m,k]*B[n,k]; K = 512.
// MODE 0: outH = bf16((C + bias[n]) * 0.125)   (Q projection)
// MODE 2: outF = C + bias[n]                   (O projection)
template <int MODE>
__global__ __launch_bounds__(256, 4)
void gemm64(const unsigned short* __restrict__ A,
            const unsigned short* __restrict__ B,
            const float* __restrict__ bias,
            float* __restrict__ outF,
            unsigned short* __restrict__ outH)
{
    __shared__ unsigned short As[64 * 32];
    __shared__ unsigned short Bs[64 * 32];

    const int tid  = threadIdx.x;
    const int w    = tid >> 6;
    const int lane = tid & 63;
    const int quad = lane >> 4;
    const int l16  = lane & 15;
    const int wm   = w >> 1, wn = w & 1;
    const int m0   = blockIdx.x * 64;
    const int n0   = blockIdx.y * 64;

    v4f acc[2][2];
#pragma unroll
    for (int i = 0; i < 2; ++i)
#pragma unroll
        for (int j = 0; j < 2; ++j)
            acc[i][j] = (v4f){0.f, 0.f, 0.f, 0.f};

    for (int kt = 0; kt < KDIM / 32; ++kt) {
        int c = w * 64 + lane;
        const unsigned short* sa = A + (size_t)(m0 + (c >> 2)) * KDIM + kt * 32 + (c & 3) * 8;
        GLD16(&As[w * 512], sa);
        const unsigned short* sb = B + (size_t)(n0 + (c >> 2)) * KDIM + kt * 32 + (c & 3) * 8;
        GLD16(&Bs[w * 512], sb);
        __syncthreads();

        v8s af[2], bf[2];
#pragma unroll
        for (int mt = 0; mt < 2; ++mt)
            af[mt] = *(const v8s*)&As[(wm * 32 + mt * 16 + l16) * 32 + quad * 8];
#pragma unroll
        for (int nt = 0; nt < 2; ++nt)
            bf[nt] = *(const v8s*)&Bs[(wn * 32 + nt * 16 + l16) * 32 + quad * 8];
#pragma unroll
        for (int mt = 0; mt < 2; ++mt)
#pragma unroll
            for (int nt = 0; nt < 2; ++nt)
                acc[mt][nt] = __builtin_amdgcn_mfma_f32_16x16x32_bf16(af[mt], bf[nt], acc[mt][nt], 0, 0, 0);
        __syncthreads();
    }

#pragma unroll
    for (int mt = 0; mt < 2; ++mt)
#pragma unroll
        for (int nt = 0; nt < 2; ++nt) {
            int col = n0 + wn * 32 + nt * 16 + l16;
            float bb = bias[col];
#pragma unroll
            for (int rg = 0; rg < 4; ++rg) {
                int row = m0 + wm * 32 + mt * 16 + quad * 4 + rg;
                float v = acc[mt][nt][rg] + bb;
                if (MODE == 0) outH[(size_t)row * EDIM + col] = f2b(v * 0.125f);
                else           outF[(size_t)row * EDIM + col] = v;
            }
        }
}

// ============================================================================
// V-GEMM, 256x256x(BK=64), 8 waves, de-lockstepped: 2 barriers per K-tile.
//   Round-2 diagnosis: with 2 barriers per PHASE, LDS-read segments (~2300
//   cyc/K-tile of CU LDS-port time) and MFMA segments (~2484 cyc) strictly
//   alternate -> MfmaUtil capped ~37%. Fix: two large segments per K-tile so
//   one wave's ds_reads/staging overlap other waves' MFMAs; compiler places
//   its own counted lgkmcnt before each MFMA use (no manual lgkmcnt(0)).
//   Per K-tile T (buf = T&1, ob = buf^1):
//    S0: LDA8(0)+LDB4(0)->bf0 | stage (T+1).A1->ob | MFMA(0,0)
//        LDB4(1)->bf1         | stage (T+1).B0->ob | MFMA(0,1)
//    BAR   (P0/P1 reads of buf.A0/B0/B1 done before S1 stages overwrite)
//    S1: LDA8(1)             | stage (T+2).A0->buf | MFMA(1,1)
//                              stage (T+2).B1->buf | MFMA(1,0)
//        vmcnt(4)  [per-wave: tile T+1's 8 loads retired]
//    BAR   (vmcnt-then-barrier => tile T+1 landed for ALL waves)
//   Barriers carry zero-cost asm memory fences (raw s_barrier is not a
//   compiler fence); MFMAs are register-only and stay free to schedule.
//   Swizzle (T2): 16B k-granule g stored at phys g^(row&7); staging
//   pre-swizzles the GLOBAL source (linear gload_lds dest, rule #21).
//   XCD map (T1): per-XCD concurrent window = 8m x 4n tiles (L2-resident).
// ============================================================================
__device__ __forceinline__ v8s ldfrag(const unsigned short* base, int r, int g) {
    return *(const v8s*)(base + (r << 6) + ((g ^ (r & 7)) << 3));
}

#define MEMBAR asm volatile("" ::: "memory")
#define BARX do { MEMBAR; __builtin_amdgcn_s_barrier(); MEMBAR; } while (0)
#define WAITV(n) asm volatile("s_waitcnt vmcnt(" #n ")" ::: "memory")

// stage one 128x64 half-tile: wave w does rows (half*128 + w*16 .. +15)
#define STAGE_H(ldsArr, bufi, half_, gptr, rowbase, ktv) do { \
    const unsigned short* s_ = (gptr) + (size_t)((rowbase) + (half_) * 128 + (w << 4) + rsub) * KDIM \
                               + (ktv) * 64 + (gsw << 3); \
    GLD16(&ldsArr[bufi][(half_) * 8192 + (w << 10)], s_); \
    GLD16(&ldsArr[bufi][(half_) * 8192 + (w << 10) + 512], s_ + 8 * KDIM); \
} while (0)

#define LDA8(mq_) do { \
    _Pragma("unroll") \
    for (int mi = 0; mi < 4; ++mi) \
        _Pragma("unroll") \
        for (int ks = 0; ks < 2; ++ks) \
            af[mi * 2 + ks] = ldfrag(abase, wm * 64 + (mq_) * 128 + mi * 16 + l16, ks * 4 + quad); \
} while (0)

#define LDB4(nq_, dst) do { \
    _Pragma("unroll") \
    for (int ni = 0; ni < 2; ++ni) \
        _Pragma("unroll") \
        for (int ks = 0; ks < 2; ++ks) \
            dst[ni * 2 + ks] = ldfrag(bbase, wn * 32 + (nq_) * 128 + ni * 16 + l16, ks * 4 + quad); \
} while (0)

#define MFMA16(ai_, bfr) do { \
    __builtin_amdgcn_s_setprio(1); \
    _Pragma("unroll") \
    for (int ks = 0; ks < 2; ++ks) \
        _Pragma("unroll") \
        for (int mi = 0; mi < 4; ++mi) \
            _Pragma("unroll") \
            for (int ni = 0; ni < 2; ++ni) \
                acc[ai_][mi][ni] = __builtin_amdgcn_mfma_f32_16x16x32_bf16( \
                    af[mi * 2 + ks], bfr[ni * 2 + ks], acc[ai_][mi][ni], 0, 0, 0); \
    __builtin_amdgcn_s_setprio(0); \
} while (0)

__global__ __launch_bounds__(512, 2)
void gemm_v(const unsigned short* __restrict__ A,
            const unsigned short* __restrict__ B,
            const float* __restrict__ bias,
            unsigned short* __restrict__ outH,
            const float* __restrict__ attn)
{
    __shared__ unsigned short As[2][16384];
    __shared__ unsigned short Bs[2][16384];

    const int tid  = threadIdx.x;
    const int w    = tid >> 6;          // wave 0..7
    const int lane = tid & 63;
    const int quad = lane >> 4;
    const int l16  = lane & 15;
    const int wm   = w >> 2;            // 0..1
    const int wn   = w & 3;             // 0..3
    const int rsub = lane >> 3;         // 0..7 (staging row-in-chunk)
    const int gsw  = (lane & 7) ^ rsub; // pre-swizzled source k-granule

    // T1: XCD c = bx&7 owns n-tiles 4c..4c+3; within XCD, concurrent window
    // of ~32 blocks = 8 m-tiles x 4 n-tiles (2 MB A + 1 MB B, L2-resident).
    const int c  = blockIdx.x & 7;
    const int j  = blockIdx.x >> 3;           // 0..127
    const int mb = (j & 7) | ((j >> 5) << 3); // 0..31
    const int nb = (j >> 3) & 3;              // 0..3
    const int m0 = mb << 8;
    const int n0 = (c * 4 + nb) << 8;

    v4f acc[4][4][2];
#pragma unroll
    for (int q = 0; q < 4; ++q)
#pragma unroll
        for (int mi = 0; mi < 4; ++mi)
#pragma unroll
            for (int ni = 0; ni < 2; ++ni)
                acc[q][mi][ni] = (v4f){0.f, 0.f, 0.f, 0.f};

    v8s af[8], bf0[4], bf1[4];

    // ---- prologue: tile 0 fully, then 1.A0, 1.B1 ----
    STAGE_H(As, 0, 0, A, m0, 0);   // 0.A0
    STAGE_H(Bs, 0, 0, B, n0, 0);   // 0.B0
    STAGE_H(As, 0, 1, A, m0, 0);   // 0.A1
    STAGE_H(Bs, 0, 1, B, n0, 0);   // 0.B1
    STAGE_H(As, 1, 0, A, m0, 1);   // 1.A0
    STAGE_H(Bs, 1, 1, B, n0, 1);   // 1.B1
    WAITV(4);                      // tile 0 landed; 2 half-tiles in flight
    BARX;

#pragma unroll
    for (int T = 0; T < KDIM / 64; ++T) {
        const unsigned short* abase = &As[T & 1][0];
        const unsigned short* bbase = &Bs[T & 1][0];
        const int ob = (T & 1) ^ 1;

        // ---- S0 ----
        LDA8(0); LDB4(0, bf0);
        if (T < 7) STAGE_H(As, ob, 1, A, m0, T + 1);       // (T+1).A1
        MFMA16(0, bf0);                                    // (mq0,nq0)
        LDB4(1, bf1);
        if (T < 7) STAGE_H(Bs, ob, 0, B, n0, T + 1);       // (T+1).B0
        MFMA16(1, bf1);                                    // (mq0,nq1)
        BARX;

        // ---- S1 ----
        LDA8(1);
        if (T < 6) STAGE_H(As, T & 1, 0, A, m0, T + 2);    // (T+2).A0 (dead slot)
        MFMA16(3, bf1);                                    // (mq1,nq1)
        if (T < 6) STAGE_H(Bs, T & 1, 1, B, n0, T + 2);    // (T+2).B1 (dead slot)
        MFMA16(2, bf0);                                    // (mq1,nq0)
        if (T < 6) { WAITV(4); } else { WAITV(0); }        // tile T+1 landed (per-wave)
        BARX;                                              // ... for all waves
    }

    // ---- epilogue: rule contraction + scrambled out1 store ----
    unsigned short* Osp = &As[0][0];    // 8 KiB, overlays dead As[0]
    const int h  = m0 >> 10;
    const int d0 = (m0 >> 4) & 63;
#pragma unroll
    for (int mq = 0; mq < 2; ++mq)
#pragma unroll
        for (int nq = 0; nq < 2; ++nq)
#pragma unroll
            for (int mi = 0; mi < 4; ++mi) {
                float4 bias4 = *(const float4*)&bias[m0 + mq * 128 + wm * 64 + mi * 16 + quad * 4];
#pragma unroll
                for (int ni = 0; ni < 2; ++ni) {
                    int tloc  = nq * 128 + wn * 32 + ni * 16 + l16;
                    float4 av = *(const float4*)&attn[(size_t)(n0 + tloc) * (HNUM * RNUM) + h * RNUM + quad * 4];
                    v4f a = acc[mq * 2 + nq][mi][ni];
                    float val = (a[0] + bias4.x) * av.x + (a[1] + bias4.y) * av.y
                              + (a[2] + bias4.z) * av.z + (a[3] + bias4.w) * av.w;
                    val += __shfl_xor(val, 16);
                    val += __shfl_xor(val, 32);
                    if (quad == 0)
                        Osp[tloc * 16 + (mq * 8 + wm * 4 + mi)] = f2b(val * 0.125f);
                }
            }
    __syncthreads();
    {
        int tl = tid >> 1, hf = tid & 1;
        int sg = n0 + tl;               // global token
        int g  = (sg >> 11) * 2048 + h * 256 + ((sg & 2047) >> 3);
        int jx = (sg & 7) * 64 + d0 + hf * 8;
        *(v8s*)&outH[(size_t)g * EDIM + jx] = *(const v8s*)&Osp[tl * 16 + hf * 8];
    }
}

// per (token, head): z_r = -0.5*mean_d(((q-k)/w)^2), softmax over 16 rules.
// grid (TOKENS/16, HNUM), block 256 = 16 tokens x 16 rules.
#define RST 72   // padded LDS row stride (floats)
__global__ __launch_bounds__(256)
void rules_softmax(const unsigned short* __restrict__ q,  // bf16 (8192 x 512)
                   const float* __restrict__ rk,
                   const float* __restrict__ rw,
                   float* __restrict__ attn)
{
    __shared__ float ql[16 * RST];
    __shared__ float rkl[16 * RST];
    __shared__ float iwl[16 * RST];
    const int h   = blockIdx.y;
    const int t0  = blockIdx.x * 16;
    const int tid = threadIdx.x;

#pragma unroll
    for (int i = 0; i < 4; ++i) {
        int jj = tid + i * 256;
        int r = jj >> 6, d = jj & 63;
        rkl[r * RST + d] = rk[h * (RNUM * DDIM) + jj];
        float wv = rw[h * (RNUM * DDIM) + jj];
        iwl[r * RST + d] = 1.0f / (wv * wv);
    }
    {
        int jj = tid * 4;
        int row = jj >> 6, d = jj & 63;
        const unsigned short* src = q + (size_t)(t0 + row) * EDIM + h * DDIM + d;
        unsigned short u0 = src[0], u1 = src[1], u2 = src[2], u3 = src[3];
        ql[row * RST + d + 0] = b2f(u0);
        ql[row * RST + d + 1] = b2f(u1);
        ql[row * RST + d + 2] = b2f(u2);
        ql[row * RST + d + 3] = b2f(u3);
    }
    __syncthreads();

    const int tl = tid >> 4;
    const int r  = tid & 15;
    const float* qrow = &ql[tl * RST];
    const float* krow = &rkl[r * RST];
    const float* wrow = &iwl[r * RST];
    float z = 0.f;
#pragma unroll
    for (int d4 = 0; d4 < 16; ++d4) {
        float4 qv = *(const float4*)&qrow[d4 * 4];
        float4 kv = *(const float4*)&krow[d4 * 4];
        float4 wv = *(const float4*)&wrow[d4 * 4];
        float a0 = qv.x - kv.x; z += a0 * a0 * wv.x;
        float a1 = qv.y - kv.y; z += a1 * a1 * wv.y;
        float a2 = qv.z - kv.z; z += a2 * a2 * wv.z;
        float a3 = qv.w - kv.w; z += a3 * a3 * wv.w;
    }
    z *= (-0.5f / 64.f);
    float mx = z;
#pragma unroll
    for (int s = 1; s < 16; s <<= 1) mx = fmaxf(mx, __shfl_xor(mx, s));
    float e = __expf(z - mx);
    float sum = e;
#pragma unroll
    for (int s = 1; s < 16; s <<= 1) sum += __shfl_xor(sum, s);
    attn[(size_t)(t0 + tl) * (HNUM * RNUM) + h * RNUM + r] = e / sum;
}

extern "C" void kernel_launch(void* const* d_in, const int* in_sizes, int n_in,
                              void* d_out, int out_size, void* d_ws, size_t ws_size,
                              hipStream_t stream) {
    const float* query = (const float*)d_in[0];
    // d_in[1] = key (unused by the reference)
    const float* value = (const float*)d_in[2];
    const float* Wq = (const float*)d_in[3];
    const float* bq = (const float*)d_in[4];
    const float* Wv = (const float*)d_in[5];
    const float* bv = (const float*)d_in[6];
    const float* Wo = (const float*)d_in[7];
    const float* bo = (const float*)d_in[8];
    const float* rk = (const float*)d_in[9];
    const float* rw = (const float*)d_in[10];

    char* ws = (char*)d_ws;
    unsigned short* qbf  = (unsigned short*)(ws);                       //  8 MiB: query bf16
    unsigned short* vbf  = (unsigned short*)(ws + (size_t)( 8 << 20));  //  8 MiB: value bf16
    unsigned short* Wqb  = (unsigned short*)(ws + (size_t)(16 << 20));  // 0.5 MiB
    unsigned short* Wvb  = (unsigned short*)(ws + (size_t)(17 << 20));  //  8 MiB
    unsigned short* Wob  = (unsigned short*)(ws + (size_t)(25 << 20));  // 0.5 MiB
    unsigned short* out1 = (unsigned short*)(ws + (size_t)(26 << 20));  //  8 MiB: scrambled bf16
    unsigned short* qf   = (unsigned short*)(ws + (size_t)(34 << 20));  //  8 MiB: q bf16
    float* attn          = (float*)(ws + (size_t)(42 << 20));           //  4 MiB: attn fp32

    dim3 blk(256);
    // 0) fp32 -> bf16 conversions
    cvt5<<<dim3(2048, 5), blk, 0, stream>>>(query, value, Wv, Wq, Wo,
                                            qbf, vbf, Wvb, Wqb, Wob,
                                            TOKENS * EDIM, TOKENS * EDIM, EDIM * RNUM * EDIM,
                                            EDIM * EDIM, EDIM * EDIM);
    // 1) q = bf16((query @ Wq^T + bq) * D^-0.5)   [64x64 tiles, 1024 blocks]
    gemm64<0><<<dim3(TOKENS / 64, EDIM / 64), blk, 0, stream>>>(qbf, Wqb, bq, nullptr, qf);
    // 2) fuzzy rule attention weights
    rules_softmax<<<dim3(TOKENS / 16, HNUM), blk, 0, stream>>>(qf, rk, rw, attn);
    // 3) transposed V-GEMM + rule contraction -> scrambled out1  [256² 2-seg]
    gemm_v<<<dim3(1024), dim3(512), 0, stream>>>(Wvb, vbf, bv, out1, attn);
    // 4) final projection -> d_out (fp32)  [64x64 tiles, 1024 blocks]
    gemm64<2><<<dim3(TOKENS / 64, EDIM / 64), blk, 0, stream>>>(out1, Wob, bo, (float*)d_out, nullptr);
}